// Round 7
// baseline (527.230 us; speedup 1.0000x reference)
//
#include <hip/hip_runtime.h>

// VQ-VAE vector quantizer, fp32-exact via MFMA-filter, MI355X — round 7.
// N=131072 rows, D=64, K=1024. d_out = quantized[8388608] + loss[1] + indices[131072].
//
// pass1: fp16 MFMA (16x16x32) computes approx scores m_j = se_j - 2^-9*(x_f16 . e_f16*1024).
//   Error bound: |m_j - true_j| <= B = g*2.05e-6 (g = sum|x_d|), incl. fp16 rounding
//   (2^-11 rel), denorm flush (abs, covered by slack), fp32 accum. Reference rounding
//   adds <=1.5e-5 pairwise. If top2 gap > T = g*5.2e-6 + 4e-5 (>2B+slack, 1.25x margin)
//   then approx argmin == reference argmin PROVABLY (unique, no tie).
// pass2: hard rows (gap <= T) rescan all 1024 codes with the exact path of rounds 1-6
//   (seq-FMA dot asc d, dist=(sx+se)-2a, ascending strict <, tie->smaller index).
// Loss: per-row fp32 contributions (easy from pass1, hard from pass2), fixed-order
//   double tree reduction -> deterministic.

typedef _Float16 f16x8 __attribute__((ext_vector_type(8)));
typedef float f32x4 __attribute__((ext_vector_type(4)));

constexpr int Dm = 64;
constexpr int Kn = 1024;
constexpr long NR = 131072;
constexpr long QE = NR * (long)Dm;   // 8388608
constexpr int RB = 64;               // rows per pass1 block
constexpr int NBLK = (int)(NR / RB); // 2048

// ws layout (bytes)
constexpr size_t SE_OFF   = 0;                      // float[1024]
constexpr size_t CBH_OFF  = 4096;                   // _Float16[65536] (scaled x1024)
constexpr size_t CNT_OFF  = CBH_OFF + 131072;       // int + pad
constexpr size_t HARD_OFF = CNT_OFF + 256;          // int[131072]
constexpr size_t RL_OFF   = HARD_OFF + 4 * 131072;  // float[131072]
constexpr size_t PART_OFF = RL_OFF + 4 * 131072;    // double[512]
constexpr size_t WS_REQ   = PART_OFF + 4096;        // ~1.19 MB

__global__ __launch_bounds__(256) void vq_prep(const float* __restrict__ cb,
                                               float* __restrict__ se,
                                               _Float16* __restrict__ cbh,
                                               int* __restrict__ cnt)
{
    int j = blockIdx.x * 256 + threadIdx.x;   // 4 blocks x 256 = 1024
    const float* e = cb + (size_t)j * Dm;
    _Float16* h = cbh + (size_t)j * Dm;
    float s = 0.f;
    #pragma unroll
    for (int d = 0; d < Dm; ++d) s = fmaf(e[d], e[d], s);  // same bits as r1-r6
    se[j] = s;
    #pragma unroll
    for (int d = 0; d < Dm; ++d) h[d] = (_Float16)(e[d] * 1024.0f);  // scale exact
    if (j == 0) *cnt = 0;
}

__global__ __launch_bounds__(256, 4) void vq_pass1(
    const float* __restrict__ inp, const float* __restrict__ cb,
    const _Float16* __restrict__ cbh, const float* __restrict__ seg,
    float* __restrict__ out, int* __restrict__ hard_list, int* __restrict__ cnt,
    float* __restrict__ row_loss)
{
    __shared__ __align__(16) _Float16 xh[RB * 72];  // padded rows (144B stride)
    __shared__ float se[Kn];
    __shared__ float gs[RB];
    __shared__ float wm1[4][RB], wm2[4][RB];
    __shared__ int   wi1[4][RB];
    __shared__ int   ridx[RB];
    __shared__ int   easyf[RB];
    __shared__ double qd[RB][4];

    const int tid = threadIdx.x;
    const long rbase = (long)blockIdx.x * RB;

    #pragma unroll
    for (int k = 0; k < 4; ++k) se[tid + 256 * k] = seg[tid + 256 * k];

    {   // stage fp16 row tile
        const int r = tid >> 2, q = tid & 3;
        const float* src = inp + (rbase + r) * Dm + q * 16;
        _Float16* dst = xh + r * 72 + q * 16;
        #pragma unroll
        for (int i = 0; i < 4; ++i) {
            float4 v = *reinterpret_cast<const float4*>(src + 4 * i);
            dst[4*i+0] = (_Float16)v.x; dst[4*i+1] = (_Float16)v.y;
            dst[4*i+2] = (_Float16)v.z; dst[4*i+3] = (_Float16)v.w;
        }
    }
    if (tid < RB) {   // g = sum|x| (bound input; fixed order)
        const float* xr = inp + (rbase + tid) * Dm;
        float g = 0.f;
        #pragma unroll
        for (int d = 0; d < Dm; ++d) g += fabsf(xr[d]);
        gs[tid] = g;
    }
    __syncthreads();

    const int w = tid >> 6, l = tid & 63;
    const int arow = l & 15, kg = l >> 4;

    // A-fragments: lane holds A[m=arow][k=kg*8+i]; 4 row-tiles of 16 rows
    f16x8 a0[4], a1[4];
    #pragma unroll
    for (int rt = 0; rt < 4; ++rt) {
        const _Float16* ap = xh + (rt * 16 + arow) * 72 + kg * 8;
        a0[rt] = *reinterpret_cast<const f16x8*>(ap);        // k 0..31
        a1[rt] = *reinterpret_cast<const f16x8*>(ap + 32);   // k 32..63
    }

    float mn1[4][4], mn2[4][4]; int ix1[4][4];
    #pragma unroll
    for (int rt = 0; rt < 4; ++rt)
        #pragma unroll
        for (int r = 0; r < 4; ++r) {
            mn1[rt][r] = __builtin_inff(); mn2[rt][r] = __builtin_inff();
            ix1[rt][r] = 0;
        }

    // wave w scans codes [w*256, w*256+256): 16 col-tiles of 16 codes
    const int code0 = w * 256 + arow;
    const _Float16* bp = cbh + (size_t)code0 * Dm + kg * 8;

    #pragma unroll 2
    for (int t = 0; t < 16; ++t) {
        // B-fragments: lane holds B[k=kg*8+i][n=arow] = E[code][k]
        const _Float16* tp = bp + t * 16 * Dm;
        f16x8 b0 = *reinterpret_cast<const f16x8*>(tp);
        f16x8 b1 = *reinterpret_cast<const f16x8*>(tp + 32);
        const int code = code0 + t * 16;
        const float sec = se[code];
        #pragma unroll
        for (int rt = 0; rt < 4; ++rt) {
            f32x4 acc = {0.f, 0.f, 0.f, 0.f};
            acc = __builtin_amdgcn_mfma_f32_16x16x32_f16(a0[rt], b0, acc, 0, 0, 0);
            acc = __builtin_amdgcn_mfma_f32_16x16x32_f16(a1[rt], b1, acc, 0, 0, 0);
            #pragma unroll
            for (int r = 0; r < 4; ++r) {   // C: row=kg*4+r (in tile rt), col=arow
                float m = fmaf(acc[r], -0.001953125f, sec);   // -2/1024 exact
                mn2[rt][r] = fminf(mn2[rt][r], fmaxf(mn1[rt][r], m));  // med3 idiom
                ix1[rt][r] = (m < mn1[rt][r]) ? code : ix1[rt][r];
                mn1[rt][r] = fminf(mn1[rt][r], m);
            }
        }
    }

    // top-2 merge across the 16 col-classes (lanes sharing kg)
    #pragma unroll
    for (int rt = 0; rt < 4; ++rt)
        #pragma unroll
        for (int r = 0; r < 4; ++r) {
            float m1v = mn1[rt][r], m2v = mn2[rt][r]; int i1v = ix1[rt][r];
            #pragma unroll
            for (int off = 1; off < 16; off <<= 1) {
                float om1 = __shfl_xor(m1v, off);
                float om2 = __shfl_xor(m2v, off);
                int   oi1 = __shfl_xor(i1v, off);
                float nm2 = fminf(fminf(m2v, om2), fmaxf(m1v, om1));
                i1v = (om1 < m1v) ? oi1 : i1v;
                m1v = fminf(m1v, om1);
                m2v = nm2;
            }
            if (arow == 0) {
                const int row = rt * 16 + kg * 4 + r;
                wm1[w][row] = m1v; wm2[w][row] = m2v; wi1[w][row] = i1v;
            }
        }
    __syncthreads();

    // merge 4 wave-subsets, easy/hard decision, hard-list append (wave 0)
    if (tid < RB) {
        float m1v = wm1[0][tid], m2v = wm2[0][tid]; int i1v = wi1[0][tid];
        #pragma unroll
        for (int q = 1; q < 4; ++q) {
            float am1 = wm1[q][tid], am2 = wm2[q][tid]; int ai = wi1[q][tid];
            float nm2 = fminf(fminf(m2v, am2), fmaxf(m1v, am1));
            i1v = (am1 < m1v) ? ai : i1v;
            m1v = fminf(m1v, am1);
            m2v = nm2;
        }
        const float T = fmaf(gs[tid], 5.2e-6f, 4.0e-5f);
        const int easy = (m2v - m1v) > T;
        ridx[tid] = i1v;
        easyf[tid] = easy;
        if (easy) out[QE + 1 + rbase + tid] = (float)i1v;
        unsigned long long hm = __ballot(!easy);
        const int nh = __popcll(hm);
        int base = 0;
        if (tid == 0 && nh) base = atomicAdd(cnt, nh);
        base = __shfl(base, 0);
        if (!easy) {
            const int pos = base + __popcll(hm & ((1ull << tid) - 1ull));
            hard_list[pos] = (int)(rbase + tid);
        }
    }
    __syncthreads();

    // easy-row epilogue (verbatim r5/r6 math): thread -> (row tid>>2, quarter tid&3)
    const int r2 = tid >> 2;
    const int dq = (tid & 3) * 16;
    if (easyf[r2]) {
        const long grow = rbase + r2;
        const float* xr2 = inp + grow * (long)Dm + dq;
        const float* q2  = cb + (size_t)ridx[r2] * Dm + dq;
        float* outq = out + grow * (long)Dm + dq;
        double s = 0.0;
        #pragma unroll
        for (int d0 = 0; d0 < 16; d0 += 4) {
            float4 xv = *reinterpret_cast<const float4*>(xr2 + d0);
            float4 qv = *reinterpret_cast<const float4*>(q2 + d0);
            float4 ov;
            float m0 = qv.x - xv.x; ov.x = xv.x + m0;   // x + (q - x)
            float m1 = qv.y - xv.y; ov.y = xv.y + m1;
            float m2 = qv.z - xv.z; ov.z = xv.z + m2;
            float m3 = qv.w - xv.w; ov.w = xv.w + m3;
            s += (double)m0*m0 + (double)m1*m1 + (double)m2*m2 + (double)m3*m3;
            *reinterpret_cast<float4*>(outq + d0) = ov;
        }
        qd[r2][tid & 3] = s;
    }
    __syncthreads();
    if (tid < RB && easyf[tid]) {
        double s = qd[tid][0] + qd[tid][1] + qd[tid][2] + qd[tid][3];  // fixed order
        row_loss[rbase + tid] = (float)s;
    }
}

// exact rescan of hard rows — reference semantics, bit-identical to rounds 1-6
__global__ __launch_bounds__(256) void vq_pass2(
    const float* __restrict__ inp, const float* __restrict__ cb,
    const float* __restrict__ seg, float* __restrict__ out,
    const int* __restrict__ hard_list, const int* __restrict__ cnt,
    float* __restrict__ row_loss)
{
    __shared__ float se[Kn];
    __shared__ float xs2[16][68];
    __shared__ float sx2[16];
    __shared__ int   hr[16];
    __shared__ float bd2[16][17];
    __shared__ int   bi2[16][17];
    __shared__ int   rix[16];
    __shared__ double qd2[16][17];

    const int tid = threadIdx.x;
    #pragma unroll
    for (int k = 0; k < 4; ++k) se[tid + 256 * k] = seg[tid + 256 * k];

    const int total = *cnt;
    const int nchunk = (total + 15) >> 4;

    for (int c = blockIdx.x; c < nchunk; c += gridDim.x) {
        __syncthreads();
        if (tid < 16) hr[tid] = (c * 16 + tid < total) ? hard_list[c * 16 + tid] : -1;
        __syncthreads();

        const int i = tid >> 4;
        const int sub = tid & 15;
        const int rowg = hr[i];

        if (rowg >= 0) {   // stage x rows fp32
            float4 v = *reinterpret_cast<const float4*>(inp + (size_t)rowg * Dm + sub * 4);
            *reinterpret_cast<float4*>(&xs2[i][sub * 4]) = v;
        }
        __syncthreads();
        if (tid < 16 && hr[tid] >= 0) {   // sx seq-FMA asc (reference order)
            float s = 0.f;
            #pragma unroll
            for (int d = 0; d < Dm; ++d) s = fmaf(xs2[tid][d], xs2[tid][d], s);
            sx2[tid] = s;
        }
        __syncthreads();

        if (rowg >= 0) {   // 16 threads/row, each an ascending 64-code range
            const float sx = sx2[i];
            float best = __builtin_inff(); int bidx = 0;
            const int cb0 = sub * 64;
            for (int j = 0; j < 64; j += 2) {
                const float* e0 = cb + (size_t)(cb0 + j) * Dm;
                float a0v = 0.f, a1v = 0.f;
                #pragma unroll
                for (int d = 0; d < Dm; ++d) {
                    a0v = fmaf(xs2[i][d], e0[d], a0v);
                    a1v = fmaf(xs2[i][d], e0[Dm + d], a1v);
                }
                float d0 = (sx + se[cb0 + j]) - 2.0f * a0v;       // exact r1-r6 formula
                float d1 = (sx + se[cb0 + j + 1]) - 2.0f * a1v;
                if (d0 < best) { best = d0; bidx = cb0 + j; }      // strict <
                if (d1 < best) { best = d1; bidx = cb0 + j + 1; }
            }
            bd2[i][sub] = best; bi2[i][sub] = bidx;
        }
        __syncthreads();
        if (tid < 16 && hr[tid] >= 0) {   // combine ranges asc, tie -> smaller idx
            float b = bd2[tid][0]; int ii = bi2[tid][0];
            #pragma unroll
            for (int q = 1; q < 16; ++q) {
                float d = bd2[tid][q]; int iq = bi2[tid][q];
                if (d < b || (d == b && iq < ii)) { b = d; ii = iq; }
            }
            rix[tid] = ii;
            out[QE + 1 + hr[tid]] = (float)ii;
        }
        __syncthreads();
        if (rowg >= 0) {   // quantized + loss partial
            const float* q2 = cb + (size_t)rix[i] * Dm + sub * 4;
            float* outq = out + (size_t)rowg * Dm + sub * 4;
            float4 xv = *reinterpret_cast<const float4*>(&xs2[i][sub * 4]);
            float4 qv = *reinterpret_cast<const float4*>(q2);
            float4 ov;
            float m0 = qv.x - xv.x; ov.x = xv.x + m0;
            float m1 = qv.y - xv.y; ov.y = xv.y + m1;
            float m2 = qv.z - xv.z; ov.z = xv.z + m2;
            float m3 = qv.w - xv.w; ov.w = xv.w + m3;
            *reinterpret_cast<float4*>(outq) = ov;
            qd2[i][sub] = (double)m0*m0 + (double)m1*m1 + (double)m2*m2 + (double)m3*m3;
        }
        __syncthreads();
        if (tid < 16 && hr[tid] >= 0) {
            double s = 0.0;
            #pragma unroll
            for (int q = 0; q < 16; ++q) s += qd2[tid][q];   // fixed order
            row_loss[hr[tid]] = (float)s;
        }
    }
}

__global__ __launch_bounds__(256) void vq_lred(const float* __restrict__ row_loss,
                                               double* __restrict__ part)
{
    __shared__ double red[256];
    const int tid = threadIdx.x;
    red[tid] = (double)row_loss[(size_t)blockIdx.x * 256 + tid];
    __syncthreads();
    for (int k = 128; k > 0; k >>= 1) {
        if (tid < k) red[tid] += red[tid + k];
        __syncthreads();
    }
    if (tid == 0) part[blockIdx.x] = red[0];
}

__global__ __launch_bounds__(256) void vq_fin2(const double* __restrict__ part,
                                               float* __restrict__ out)
{
    __shared__ double red[256];
    const int tid = threadIdx.x;
    red[tid] = part[tid] + part[tid + 256];
    __syncthreads();
    for (int k = 128; k > 0; k >>= 1) {
        if (tid < k) red[tid] += red[tid + k];
        __syncthreads();
    }
    if (tid == 0) {
        float m = (float)(red[0] / (double)QE);
        out[QE] = m + 0.25f * m;   // q_loss + 0.25 * e_loss
    }
}

// ---------------- fallback (round-5 kernels, used only if ws too small) -------
constexpr int CHf = 64;
constexpr int SP4 = 17;

__global__ __launch_bounds__(256) void vq_norms_fb(const float* __restrict__ cb,
                                                   float* __restrict__ se)
{
    int j = blockIdx.x * 256 + threadIdx.x;
    const float* e = cb + (size_t)j * Dm;
    float s = 0.f;
    #pragma unroll
    for (int d = 0; d < Dm; ++d) s = fmaf(e[d], e[d], s);
    se[j] = s;
}

__global__ __launch_bounds__(256) void vq_main_fb(const float* __restrict__ inp,
                                                  const float* __restrict__ cb,
                                                  const float* __restrict__ seg,
                                                  float* __restrict__ out,
                                                  double* __restrict__ part)
{
    __shared__ float4 xs[RB * SP4];
    __shared__ float4 es[CHf * SP4];
    __shared__ float  ses[Kn];
    __shared__ float  sxs[RB];
    __shared__ float  bd[RB * 17];
    __shared__ int    bi[RB * 17];
    __shared__ int    comb[RB];
    __shared__ double red[256];

    const int tid = threadIdx.x;
    const int tr = tid & 15;
    const int tc = tid >> 4;
    {
        const float4* src = reinterpret_cast<const float4*>(inp + (size_t)blockIdx.x * RB * Dm);
        #pragma unroll
        for (int r = 0; r < 4; ++r) {
            int g = r * 256 + tid;
            xs[(g >> 4) * SP4 + (g & 15)] = src[g];
        }
        #pragma unroll
        for (int k = 0; k < 4; ++k) ses[tid + 256 * k] = seg[tid + 256 * k];
    }
    __syncthreads();
    if (tid < RB) {
        const float* xr = reinterpret_cast<const float*>(&xs[tid * SP4]);
        float s = 0.f;
        #pragma unroll
        for (int d = 0; d < Dm; ++d) s = fmaf(xr[d], xr[d], s);
        sxs[tid] = s;
    }
    __syncthreads();
    float sxr[4];
    #pragma unroll
    for (int rr = 0; rr < 4; ++rr) sxr[rr] = sxs[tr + 16 * rr];
    float best[4]; int bidx[4];
    #pragma unroll
    for (int rr = 0; rr < 4; ++rr) { best[rr] = __builtin_inff(); bidx[rr] = 0; }
    const float4* gcb = reinterpret_cast<const float4*>(cb);
    for (int ch = 0; ch < Kn / CHf; ++ch) {
        __syncthreads();
        #pragma unroll
        for (int r = 0; r < 4; ++r) {
            int g = r * 256 + tid;
            es[(g >> 4) * SP4 + (g & 15)] = gcb[(size_t)ch * (CHf * Dm / 4) + g];
        }
        __syncthreads();
        float acc[4][4];
        #pragma unroll
        for (int rr = 0; rr < 4; ++rr)
            #pragma unroll
            for (int cc = 0; cc < 4; ++cc) acc[rr][cc] = 0.f;
        #pragma unroll 4
        for (int db = 0; db < 16; ++db) {
            float4 xf[4], ef[4];
            #pragma unroll
            for (int rr = 0; rr < 4; ++rr) xf[rr] = xs[(tr + 16 * rr) * SP4 + db];
            #pragma unroll
            for (int cc = 0; cc < 4; ++cc) ef[cc] = es[(tc + 16 * cc) * SP4 + db];
            #pragma unroll
            for (int rr = 0; rr < 4; ++rr)
                #pragma unroll
                for (int cc = 0; cc < 4; ++cc) {
                    float a = acc[rr][cc];
                    a = fmaf(xf[rr].x, ef[cc].x, a);
                    a = fmaf(xf[rr].y, ef[cc].y, a);
                    a = fmaf(xf[rr].z, ef[cc].z, a);
                    a = fmaf(xf[rr].w, ef[cc].w, a);
                    acc[rr][cc] = a;
                }
        }
        const int cbase = ch * CHf;
        #pragma unroll
        for (int cc = 0; cc < 4; ++cc) {
            const int code = cbase + tc + 16 * cc;
            const float sec = ses[code];
            #pragma unroll
            for (int rr = 0; rr < 4; ++rr) {
                float dist = (sxr[rr] + sec) - 2.0f * acc[rr][cc];
                if (dist < best[rr]) { best[rr] = dist; bidx[rr] = code; }
            }
        }
    }
    #pragma unroll
    for (int rr = 0; rr < 4; ++rr) {
        int row = tr + 16 * rr;
        bd[row * 17 + tc] = best[rr];
        bi[row * 17 + tc] = bidx[rr];
    }
    __syncthreads();
    if (tid < RB) {
        float b = bd[tid * 17]; int ii = bi[tid * 17];
        #pragma unroll
        for (int q = 1; q < 16; ++q) {
            float d = bd[tid * 17 + q]; int iq = bi[tid * 17 + q];
            if (d < b || (d == b && iq < ii)) { b = d; ii = iq; }
        }
        comb[tid] = ii;
        out[QE + 1 + (long)blockIdx.x * RB + tid] = (float)ii;
    }
    __syncthreads();
    const int r2 = tid >> 2;
    const int dq = (tid & 3) * 16;
    const long grow = (long)blockIdx.x * RB + r2;
    const float* xr2 = inp + grow * (long)Dm + dq;
    const float* q2  = cb + (size_t)comb[r2] * Dm + dq;
    float* outq = out + grow * (long)Dm + dq;
    double s = 0.0;
    #pragma unroll
    for (int d0 = 0; d0 < 16; d0 += 4) {
        float4 xv = *reinterpret_cast<const float4*>(xr2 + d0);
        float4 qv = *reinterpret_cast<const float4*>(q2 + d0);
        float4 ov;
        float m0 = qv.x - xv.x; ov.x = xv.x + m0;
        float m1 = qv.y - xv.y; ov.y = xv.y + m1;
        float m2 = qv.z - xv.z; ov.z = xv.z + m2;
        float m3 = qv.w - xv.w; ov.w = xv.w + m3;
        s += (double)m0*m0 + (double)m1*m1 + (double)m2*m2 + (double)m3*m3;
        *reinterpret_cast<float4*>(outq + d0) = ov;
    }
    red[tid] = s;
    __syncthreads();
    for (int k = 128; k > 0; k >>= 1) {
        if (tid < k) red[tid] += red[tid + k];
        __syncthreads();
    }
    if (tid == 0) part[blockIdx.x] = red[0];
}

__global__ __launch_bounds__(256) void vq_fin_fb(const double* __restrict__ part,
                                                 float* __restrict__ out)
{
    __shared__ double red[256];
    const int tid = threadIdx.x;
    double s = 0.0;
    #pragma unroll
    for (int k = 0; k < 8; ++k) s += part[tid + 256 * k];
    red[tid] = s;
    __syncthreads();
    for (int k = 128; k > 0; k >>= 1) {
        if (tid < k) red[tid] += red[tid + k];
        __syncthreads();
    }
    if (tid == 0) {
        float m = (float)(red[0] / (double)QE);
        out[QE] = m + 0.25f * m;
    }
}

extern "C" void kernel_launch(void* const* d_in, const int* in_sizes, int n_in,
                              void* d_out, int out_size, void* d_ws, size_t ws_size,
                              hipStream_t stream)
{
    const float* inp = (const float*)d_in[0];
    const float* cb  = (const float*)d_in[1];
    float* out = (float*)d_out;
    char* ws = (char*)d_ws;

    if (ws_size >= WS_REQ) {
        float*    se   = (float*)(ws + SE_OFF);
        _Float16* cbh  = (_Float16*)(ws + CBH_OFF);
        int*      cnt  = (int*)(ws + CNT_OFF);
        int*      hard = (int*)(ws + HARD_OFF);
        float*    rl   = (float*)(ws + RL_OFF);
        double*   part = (double*)(ws + PART_OFF);

        vq_prep<<<4, 256, 0, stream>>>(cb, se, cbh, cnt);
        vq_pass1<<<NBLK, 256, 0, stream>>>(inp, cb, cbh, se, out, hard, cnt, rl);
        vq_pass2<<<1024, 256, 0, stream>>>(inp, cb, se, out, hard, cnt, rl);
        vq_lred<<<512, 256, 0, stream>>>(rl, part);
        vq_fin2<<<1, 256, 0, stream>>>(part, out);
    } else {
        float*  se   = (float*)ws;
        double* part = (double*)(ws + 4096);
        vq_norms_fb<<<4, 256, 0, stream>>>(cb, se);
        vq_main_fb<<<NBLK, 256, 0, stream>>>(inp, cb, se, out, part);
        vq_fin_fb<<<1, 256, 0, stream>>>(part, out);
    }
}

// Round 8
// 139.991 us; speedup vs baseline: 3.7662x; 3.7662x over previous
//
#include <hip/hip_runtime.h>

// VQ-VAE vector quantizer, fp32-exact via MFMA-filter, MI355X — round 8.
// N=131072 rows, D=64, K=1024. d_out = quantized[8388608] + loss[1] + indices[131072].
//
// pass1 (UNCHANGED from round 7, absmax 0.0): fp16 MFMA approx scores
//   m_j = se_j - 2^-9*(x_f16 . e_f16*1024); top-2 + provable gap test
//   T = g*5.2e-6 + 4e-5. Easy rows finished in-place; hard rows listed.
// pass2 (REWRITTEN): round-5 gathered-GEMM exact rescan. Grid-stride chunks of
//   64 hard rows; LDS row tile + LDS codebook chunks + 4x4 register tile;
//   seq-FMA asc d, dist=(sx+se)-2a, ascending strict <, tie->smaller index —
//   bit-identical to the 7x-passing exact path. (Round 7's pass2 was 456 us /
//   VALUBusy 6%: per-lane divergent codebook loads + 4096-FMA serial chains.)
// Loss: per-row fp32 contribs -> fixed-order double tree -> deterministic.

typedef _Float16 f16x8 __attribute__((ext_vector_type(8)));
typedef float f32x4 __attribute__((ext_vector_type(4)));

constexpr int Dm = 64;
constexpr int Kn = 1024;
constexpr long NR = 131072;
constexpr long QE = NR * (long)Dm;   // 8388608
constexpr int RB = 64;               // rows per block
constexpr int NBLK = (int)(NR / RB); // 2048
constexpr int CH = 64;               // codes per LDS chunk (pass2)
constexpr int NCH = Kn / CH;         // 16
constexpr int SP4 = 17;              // padded row stride in float4s

// ws layout (bytes)
constexpr size_t SE_OFF   = 0;                      // float[1024]
constexpr size_t CBH_OFF  = 4096;                   // _Float16[65536] (scaled x1024)
constexpr size_t CNT_OFF  = CBH_OFF + 131072;       // int + pad
constexpr size_t HARD_OFF = CNT_OFF + 256;          // int[131072]
constexpr size_t RL_OFF   = HARD_OFF + 4 * 131072;  // float[131072]
constexpr size_t PART_OFF = RL_OFF + 4 * 131072;    // double[512]
constexpr size_t WS_REQ   = PART_OFF + 4096;        // ~1.19 MB

__global__ __launch_bounds__(256) void vq_prep(const float* __restrict__ cb,
                                               float* __restrict__ se,
                                               _Float16* __restrict__ cbh,
                                               int* __restrict__ cnt)
{
    int j = blockIdx.x * 256 + threadIdx.x;   // 4 blocks x 256 = 1024
    const float* e = cb + (size_t)j * Dm;
    _Float16* h = cbh + (size_t)j * Dm;
    float s = 0.f;
    #pragma unroll
    for (int d = 0; d < Dm; ++d) s = fmaf(e[d], e[d], s);  // same bits as r1-r7
    se[j] = s;
    #pragma unroll
    for (int d = 0; d < Dm; ++d) h[d] = (_Float16)(e[d] * 1024.0f);  // scale exact
    if (j == 0) *cnt = 0;
}

__global__ __launch_bounds__(256, 4) void vq_pass1(
    const float* __restrict__ inp, const float* __restrict__ cb,
    const _Float16* __restrict__ cbh, const float* __restrict__ seg,
    float* __restrict__ out, int* __restrict__ hard_list, int* __restrict__ cnt,
    float* __restrict__ row_loss)
{
    __shared__ __align__(16) _Float16 xh[RB * 72];  // padded rows (144B stride)
    __shared__ float se[Kn];
    __shared__ float gs[RB];
    __shared__ float wm1[4][RB], wm2[4][RB];
    __shared__ int   wi1[4][RB];
    __shared__ int   ridx[RB];
    __shared__ int   easyf[RB];
    __shared__ double qd[RB][4];

    const int tid = threadIdx.x;
    const long rbase = (long)blockIdx.x * RB;

    #pragma unroll
    for (int k = 0; k < 4; ++k) se[tid + 256 * k] = seg[tid + 256 * k];

    {   // stage fp16 row tile
        const int r = tid >> 2, q = tid & 3;
        const float* src = inp + (rbase + r) * Dm + q * 16;
        _Float16* dst = xh + r * 72 + q * 16;
        #pragma unroll
        for (int i = 0; i < 4; ++i) {
            float4 v = *reinterpret_cast<const float4*>(src + 4 * i);
            dst[4*i+0] = (_Float16)v.x; dst[4*i+1] = (_Float16)v.y;
            dst[4*i+2] = (_Float16)v.z; dst[4*i+3] = (_Float16)v.w;
        }
    }
    if (tid < RB) {   // g = sum|x| (bound input; fixed order)
        const float* xr = inp + (rbase + tid) * Dm;
        float g = 0.f;
        #pragma unroll
        for (int d = 0; d < Dm; ++d) g += fabsf(xr[d]);
        gs[tid] = g;
    }
    __syncthreads();

    const int w = tid >> 6, l = tid & 63;
    const int arow = l & 15, kg = l >> 4;

    // A-fragments: lane holds A[m=arow][k=kg*8+i]; 4 row-tiles of 16 rows
    f16x8 a0[4], a1[4];
    #pragma unroll
    for (int rt = 0; rt < 4; ++rt) {
        const _Float16* ap = xh + (rt * 16 + arow) * 72 + kg * 8;
        a0[rt] = *reinterpret_cast<const f16x8*>(ap);        // k 0..31
        a1[rt] = *reinterpret_cast<const f16x8*>(ap + 32);   // k 32..63
    }

    float mn1[4][4], mn2[4][4]; int ix1[4][4];
    #pragma unroll
    for (int rt = 0; rt < 4; ++rt)
        #pragma unroll
        for (int r = 0; r < 4; ++r) {
            mn1[rt][r] = __builtin_inff(); mn2[rt][r] = __builtin_inff();
            ix1[rt][r] = 0;
        }

    // wave w scans codes [w*256, w*256+256): 16 col-tiles of 16 codes
    const int code0 = w * 256 + arow;
    const _Float16* bp = cbh + (size_t)code0 * Dm + kg * 8;

    #pragma unroll 2
    for (int t = 0; t < 16; ++t) {
        // B-fragments: lane holds B[k=kg*8+i][n=arow] = E[code][k]
        const _Float16* tp = bp + t * 16 * Dm;
        f16x8 b0 = *reinterpret_cast<const f16x8*>(tp);
        f16x8 b1 = *reinterpret_cast<const f16x8*>(tp + 32);
        const int code = code0 + t * 16;
        const float sec = se[code];
        #pragma unroll
        for (int rt = 0; rt < 4; ++rt) {
            f32x4 acc = {0.f, 0.f, 0.f, 0.f};
            acc = __builtin_amdgcn_mfma_f32_16x16x32_f16(a0[rt], b0, acc, 0, 0, 0);
            acc = __builtin_amdgcn_mfma_f32_16x16x32_f16(a1[rt], b1, acc, 0, 0, 0);
            #pragma unroll
            for (int r = 0; r < 4; ++r) {   // C: row=kg*4+r (in tile rt), col=arow
                float m = fmaf(acc[r], -0.001953125f, sec);   // -2/1024 exact
                mn2[rt][r] = fminf(mn2[rt][r], fmaxf(mn1[rt][r], m));  // med3 idiom
                ix1[rt][r] = (m < mn1[rt][r]) ? code : ix1[rt][r];
                mn1[rt][r] = fminf(mn1[rt][r], m);
            }
        }
    }

    // top-2 merge across the 16 col-classes (lanes sharing kg)
    #pragma unroll
    for (int rt = 0; rt < 4; ++rt)
        #pragma unroll
        for (int r = 0; r < 4; ++r) {
            float m1v = mn1[rt][r], m2v = mn2[rt][r]; int i1v = ix1[rt][r];
            #pragma unroll
            for (int off = 1; off < 16; off <<= 1) {
                float om1 = __shfl_xor(m1v, off);
                float om2 = __shfl_xor(m2v, off);
                int   oi1 = __shfl_xor(i1v, off);
                float nm2 = fminf(fminf(m2v, om2), fmaxf(m1v, om1));
                i1v = (om1 < m1v) ? oi1 : i1v;
                m1v = fminf(m1v, om1);
                m2v = nm2;
            }
            if (arow == 0) {
                const int row = rt * 16 + kg * 4 + r;
                wm1[w][row] = m1v; wm2[w][row] = m2v; wi1[w][row] = i1v;
            }
        }
    __syncthreads();

    // merge 4 wave-subsets, easy/hard decision, hard-list append (wave 0)
    if (tid < RB) {
        float m1v = wm1[0][tid], m2v = wm2[0][tid]; int i1v = wi1[0][tid];
        #pragma unroll
        for (int q = 1; q < 4; ++q) {
            float am1 = wm1[q][tid], am2 = wm2[q][tid]; int ai = wi1[q][tid];
            float nm2 = fminf(fminf(m2v, am2), fmaxf(m1v, am1));
            i1v = (am1 < m1v) ? ai : i1v;
            m1v = fminf(m1v, am1);
            m2v = nm2;
        }
        const float T = fmaf(gs[tid], 5.2e-6f, 4.0e-5f);
        const int easy = (m2v - m1v) > T;
        ridx[tid] = i1v;
        easyf[tid] = easy;
        if (easy) out[QE + 1 + rbase + tid] = (float)i1v;
        unsigned long long hm = __ballot(!easy);
        const int nh = __popcll(hm);
        int base = 0;
        if (tid == 0 && nh) base = atomicAdd(cnt, nh);
        base = __shfl(base, 0);
        if (!easy) {
            const int pos = base + __popcll(hm & ((1ull << tid) - 1ull));
            hard_list[pos] = (int)(rbase + tid);
        }
    }
    __syncthreads();

    // easy-row epilogue (verbatim r5/r6 math): thread -> (row tid>>2, quarter tid&3)
    const int r2 = tid >> 2;
    const int dq = (tid & 3) * 16;
    if (easyf[r2]) {
        const long grow = rbase + r2;
        const float* xr2 = inp + grow * (long)Dm + dq;
        const float* q2  = cb + (size_t)ridx[r2] * Dm + dq;
        float* outq = out + grow * (long)Dm + dq;
        double s = 0.0;
        #pragma unroll
        for (int d0 = 0; d0 < 16; d0 += 4) {
            float4 xv = *reinterpret_cast<const float4*>(xr2 + d0);
            float4 qv = *reinterpret_cast<const float4*>(q2 + d0);
            float4 ov;
            float m0 = qv.x - xv.x; ov.x = xv.x + m0;   // x + (q - x)
            float m1 = qv.y - xv.y; ov.y = xv.y + m1;
            float m2 = qv.z - xv.z; ov.z = xv.z + m2;
            float m3 = qv.w - xv.w; ov.w = xv.w + m3;
            s += (double)m0*m0 + (double)m1*m1 + (double)m2*m2 + (double)m3*m3;
            *reinterpret_cast<float4*>(outq + d0) = ov;
        }
        qd[r2][tid & 3] = s;
    }
    __syncthreads();
    if (tid < RB && easyf[tid]) {
        double s = qd[tid][0] + qd[tid][1] + qd[tid][2] + qd[tid][3];  // fixed order
        row_loss[rbase + tid] = (float)s;
    }
}

// pass2: exact rescan of hard rows, round-5 gathered-GEMM structure.
// Bit-identical exact path: seq-FMA asc d, dist=(sx+se)-2a, asc strict <,
// cross-thread tie -> smaller index.
__global__ __launch_bounds__(256) void vq_pass2(
    const float* __restrict__ inp, const float* __restrict__ cb,
    const float* __restrict__ seg, float* __restrict__ out,
    const int* __restrict__ hard_list, const int* __restrict__ cnt,
    float* __restrict__ row_loss)
{
    __shared__ float4 xs[RB * SP4];   // gathered hard rows
    __shared__ float4 es[CH * SP4];   // codebook chunk
    __shared__ float  ses[Kn];
    __shared__ float  sxs[RB];
    __shared__ int    hr[RB];
    __shared__ float  bd[RB * 17];
    __shared__ int    bi[RB * 17];
    __shared__ int    comb[RB];
    __shared__ double qd[RB][4];

    const int tid = threadIdx.x;
    const int tr = tid & 15;          // row-group id
    const int tc = tid >> 4;          // code-group id

    #pragma unroll
    for (int k = 0; k < 4; ++k) ses[tid + 256 * k] = seg[tid + 256 * k];

    const int total = *cnt;
    const int nchunk = (total + RB - 1) / RB;
    const float4* gcb = reinterpret_cast<const float4*>(cb);

    for (int c = blockIdx.x; c < nchunk; c += gridDim.x) {
        __syncthreads();   // LDS reuse guard (also orders ses on first iter)
        if (tid < RB) {
            int gi = c * RB + tid;
            hr[tid] = (gi < total) ? hard_list[gi] : -1;
        }
        __syncthreads();

        // gather-stage row tile: 16 float4 = one 256B row per 16-lane group
        #pragma unroll
        for (int r = 0; r < 4; ++r) {
            int g = r * 256 + tid;               // 0..1023
            int row = g >> 4, col = g & 15;
            int gr = hr[row];
            float4 v = {0.f, 0.f, 0.f, 0.f};
            if (gr >= 0)
                v = *reinterpret_cast<const float4*>(inp + (size_t)gr * Dm + col * 4);
            xs[row * SP4 + col] = v;
        }
        __syncthreads();

        if (tid < RB) {   // sx seq-FMA asc d (reference op order)
            const float* xr = reinterpret_cast<const float*>(&xs[tid * SP4]);
            float s = 0.f;
            #pragma unroll
            for (int d = 0; d < Dm; ++d) s = fmaf(xr[d], xr[d], s);
            sxs[tid] = s;
        }
        __syncthreads();

        float sxr[4];
        #pragma unroll
        for (int rr = 0; rr < 4; ++rr) sxr[rr] = sxs[tr + 16 * rr];

        float best[4]; int bidx[4];
        #pragma unroll
        for (int rr = 0; rr < 4; ++rr) { best[rr] = __builtin_inff(); bidx[rr] = 0; }

        for (int ch = 0; ch < NCH; ++ch) {
            __syncthreads();
            #pragma unroll
            for (int r = 0; r < 4; ++r) {        // stage codebook chunk
                int g = r * 256 + tid;
                es[(g >> 4) * SP4 + (g & 15)] = gcb[(size_t)ch * (CH * Dm / 4) + g];
            }
            __syncthreads();

            float acc[4][4];
            #pragma unroll
            for (int rr = 0; rr < 4; ++rr)
                #pragma unroll
                for (int cc = 0; cc < 4; ++cc) acc[rr][cc] = 0.f;

            #pragma unroll 4
            for (int db = 0; db < 16; ++db) {    // d-block of 4, ascending
                float4 xf[4], ef[4];
                #pragma unroll
                for (int rr = 0; rr < 4; ++rr) xf[rr] = xs[(tr + 16 * rr) * SP4 + db];
                #pragma unroll
                for (int cc = 0; cc < 4; ++cc) ef[cc] = es[(tc + 16 * cc) * SP4 + db];
                #pragma unroll
                for (int rr = 0; rr < 4; ++rr)
                    #pragma unroll
                    for (int cc = 0; cc < 4; ++cc) {
                        float a = acc[rr][cc];
                        a = fmaf(xf[rr].x, ef[cc].x, a);   // d asc, in order
                        a = fmaf(xf[rr].y, ef[cc].y, a);
                        a = fmaf(xf[rr].z, ef[cc].z, a);
                        a = fmaf(xf[rr].w, ef[cc].w, a);
                        acc[rr][cc] = a;
                    }
            }

            const int cbase = ch * CH;
            #pragma unroll
            for (int cc = 0; cc < 4; ++cc) {     // codes ascending per thread
                const int code = cbase + tc + 16 * cc;
                const float sec = ses[code];
                #pragma unroll
                for (int rr = 0; rr < 4; ++rr) {
                    float dist = (sxr[rr] + sec) - 2.0f * acc[rr][cc];  // exact formula
                    if (dist < best[rr]) { best[rr] = dist; bidx[rr] = code; }
                }
            }
        }

        #pragma unroll
        for (int rr = 0; rr < 4; ++rr) {
            int row = tr + 16 * rr;
            bd[row * 17 + tc] = best[rr];
            bi[row * 17 + tc] = bidx[rr];
        }
        __syncthreads();

        if (tid < RB && hr[tid] >= 0) {   // combine: min dist, tie -> smaller index
            float b = bd[tid * 17]; int ii = bi[tid * 17];
            #pragma unroll
            for (int q = 1; q < 16; ++q) {
                float d = bd[tid * 17 + q]; int iq = bi[tid * 17 + q];
                if (d < b || (d == b && iq < ii)) { b = d; ii = iq; }
            }
            comb[tid] = ii;
            out[QE + 1 + hr[tid]] = (float)ii;
        }
        __syncthreads();

        // scatter epilogue: thread -> (row tid>>2, quarter tid&3)
        const int r2 = tid >> 2;
        const int dq = (tid & 3) * 16;
        if (hr[r2] >= 0) {
            const long grow = hr[r2];
            const float* xr2 = inp + grow * (long)Dm + dq;
            const float* q2  = cb + (size_t)comb[r2] * Dm + dq;
            float* outq = out + grow * (long)Dm + dq;
            double s = 0.0;
            #pragma unroll
            for (int d0 = 0; d0 < 16; d0 += 4) {
                float4 xv = *reinterpret_cast<const float4*>(xr2 + d0);
                float4 qv = *reinterpret_cast<const float4*>(q2 + d0);
                float4 ov;
                float m0 = qv.x - xv.x; ov.x = xv.x + m0;   // x + (q - x)
                float m1 = qv.y - xv.y; ov.y = xv.y + m1;
                float m2 = qv.z - xv.z; ov.z = xv.z + m2;
                float m3 = qv.w - xv.w; ov.w = xv.w + m3;
                s += (double)m0*m0 + (double)m1*m1 + (double)m2*m2 + (double)m3*m3;
                *reinterpret_cast<float4*>(outq + d0) = ov;
            }
            qd[r2][tid & 3] = s;
        }
        __syncthreads();
        if (tid < RB && hr[tid] >= 0) {
            double s = qd[tid][0] + qd[tid][1] + qd[tid][2] + qd[tid][3];  // fixed order
            row_loss[hr[tid]] = (float)s;
        }
    }
}

__global__ __launch_bounds__(256) void vq_lred(const float* __restrict__ row_loss,
                                               double* __restrict__ part)
{
    __shared__ double red[256];
    const int tid = threadIdx.x;
    red[tid] = (double)row_loss[(size_t)blockIdx.x * 256 + tid];
    __syncthreads();
    for (int k = 128; k > 0; k >>= 1) {
        if (tid < k) red[tid] += red[tid + k];
        __syncthreads();
    }
    if (tid == 0) part[blockIdx.x] = red[0];
}

__global__ __launch_bounds__(256) void vq_fin2(const double* __restrict__ part,
                                               float* __restrict__ out)
{
    __shared__ double red[256];
    const int tid = threadIdx.x;
    red[tid] = part[tid] + part[tid + 256];
    __syncthreads();
    for (int k = 128; k > 0; k >>= 1) {
        if (tid < k) red[tid] += red[tid + k];
        __syncthreads();
    }
    if (tid == 0) {
        float m = (float)(red[0] / (double)QE);
        out[QE] = m + 0.25f * m;   // q_loss + 0.25 * e_loss
    }
}

// ---------------- fallback (round-5 kernels, used only if ws too small) -------
__global__ __launch_bounds__(256) void vq_norms_fb(const float* __restrict__ cb,
                                                   float* __restrict__ se)
{
    int j = blockIdx.x * 256 + threadIdx.x;
    const float* e = cb + (size_t)j * Dm;
    float s = 0.f;
    #pragma unroll
    for (int d = 0; d < Dm; ++d) s = fmaf(e[d], e[d], s);
    se[j] = s;
}

__global__ __launch_bounds__(256) void vq_main_fb(const float* __restrict__ inp,
                                                  const float* __restrict__ cb,
                                                  const float* __restrict__ seg,
                                                  float* __restrict__ out,
                                                  double* __restrict__ part)
{
    __shared__ float4 xs[RB * SP4];
    __shared__ float4 es[CH * SP4];
    __shared__ float  ses[Kn];
    __shared__ float  sxs[RB];
    __shared__ float  bd[RB * 17];
    __shared__ int    bi[RB * 17];
    __shared__ int    comb[RB];
    __shared__ double red[256];

    const int tid = threadIdx.x;
    const int tr = tid & 15;
    const int tc = tid >> 4;
    {
        const float4* src = reinterpret_cast<const float4*>(inp + (size_t)blockIdx.x * RB * Dm);
        #pragma unroll
        for (int r = 0; r < 4; ++r) {
            int g = r * 256 + tid;
            xs[(g >> 4) * SP4 + (g & 15)] = src[g];
        }
        #pragma unroll
        for (int k = 0; k < 4; ++k) ses[tid + 256 * k] = seg[tid + 256 * k];
    }
    __syncthreads();
    if (tid < RB) {
        const float* xr = reinterpret_cast<const float*>(&xs[tid * SP4]);
        float s = 0.f;
        #pragma unroll
        for (int d = 0; d < Dm; ++d) s = fmaf(xr[d], xr[d], s);
        sxs[tid] = s;
    }
    __syncthreads();
    float sxr[4];
    #pragma unroll
    for (int rr = 0; rr < 4; ++rr) sxr[rr] = sxs[tr + 16 * rr];
    float best[4]; int bidx[4];
    #pragma unroll
    for (int rr = 0; rr < 4; ++rr) { best[rr] = __builtin_inff(); bidx[rr] = 0; }
    const float4* gcb = reinterpret_cast<const float4*>(cb);
    for (int ch = 0; ch < NCH; ++ch) {
        __syncthreads();
        #pragma unroll
        for (int r = 0; r < 4; ++r) {
            int g = r * 256 + tid;
            es[(g >> 4) * SP4 + (g & 15)] = gcb[(size_t)ch * (CH * Dm / 4) + g];
        }
        __syncthreads();
        float acc[4][4];
        #pragma unroll
        for (int rr = 0; rr < 4; ++rr)
            #pragma unroll
            for (int cc = 0; cc < 4; ++cc) acc[rr][cc] = 0.f;
        #pragma unroll 4
        for (int db = 0; db < 16; ++db) {
            float4 xf[4], ef[4];
            #pragma unroll
            for (int rr = 0; rr < 4; ++rr) xf[rr] = xs[(tr + 16 * rr) * SP4 + db];
            #pragma unroll
            for (int cc = 0; cc < 4; ++cc) ef[cc] = es[(tc + 16 * cc) * SP4 + db];
            #pragma unroll
            for (int rr = 0; rr < 4; ++rr)
                #pragma unroll
                for (int cc = 0; cc < 4; ++cc) {
                    float a = acc[rr][cc];
                    a = fmaf(xf[rr].x, ef[cc].x, a);
                    a = fmaf(xf[rr].y, ef[cc].y, a);
                    a = fmaf(xf[rr].z, ef[cc].z, a);
                    a = fmaf(xf[rr].w, ef[cc].w, a);
                    acc[rr][cc] = a;
                }
        }
        const int cbase = ch * CH;
        #pragma unroll
        for (int cc = 0; cc < 4; ++cc) {
            const int code = cbase + tc + 16 * cc;
            const float sec = ses[code];
            #pragma unroll
            for (int rr = 0; rr < 4; ++rr) {
                float dist = (sxr[rr] + sec) - 2.0f * acc[rr][cc];
                if (dist < best[rr]) { best[rr] = dist; bidx[rr] = code; }
            }
        }
    }
    #pragma unroll
    for (int rr = 0; rr < 4; ++rr) {
        int row = tr + 16 * rr;
        bd[row * 17 + tc] = best[rr];
        bi[row * 17 + tc] = bidx[rr];
    }
    __syncthreads();
    if (tid < RB) {
        float b = bd[tid * 17]; int ii = bi[tid * 17];
        #pragma unroll
        for (int q = 1; q < 16; ++q) {
            float d = bd[tid * 17 + q]; int iq = bi[tid * 17 + q];
            if (d < b || (d == b && iq < ii)) { b = d; ii = iq; }
        }
        comb[tid] = ii;
        out[QE + 1 + (long)blockIdx.x * RB + tid] = (float)ii;
    }
    __syncthreads();
    const int r2 = tid >> 2;
    const int dq = (tid & 3) * 16;
    const long grow = (long)blockIdx.x * RB + r2;
    const float* xr2 = inp + grow * (long)Dm + dq;
    const float* q2  = cb + (size_t)comb[r2] * Dm + dq;
    float* outq = out + grow * (long)Dm + dq;
    double s = 0.0;
    #pragma unroll
    for (int d0 = 0; d0 < 16; d0 += 4) {
        float4 xv = *reinterpret_cast<const float4*>(xr2 + d0);
        float4 qv = *reinterpret_cast<const float4*>(q2 + d0);
        float4 ov;
        float m0 = qv.x - xv.x; ov.x = xv.x + m0;
        float m1 = qv.y - xv.y; ov.y = xv.y + m1;
        float m2 = qv.z - xv.z; ov.z = xv.z + m2;
        float m3 = qv.w - xv.w; ov.w = xv.w + m3;
        s += (double)m0*m0 + (double)m1*m1 + (double)m2*m2 + (double)m3*m3;
        *reinterpret_cast<float4*>(outq + d0) = ov;
    }
    red[tid] = s;
    __syncthreads();
    for (int k = 128; k > 0; k >>= 1) {
        if (tid < k) red[tid] += red[tid + k];
        __syncthreads();
    }
    if (tid == 0) part[blockIdx.x] = red[0];
}

__global__ __launch_bounds__(256) void vq_fin_fb(const double* __restrict__ part,
                                                 float* __restrict__ out)
{
    __shared__ double red[256];
    const int tid = threadIdx.x;
    double s = 0.0;
    #pragma unroll
    for (int k = 0; k < 8; ++k) s += part[tid + 256 * k];
    red[tid] = s;
    __syncthreads();
    for (int k = 128; k > 0; k >>= 1) {
        if (tid < k) red[tid] += red[tid + k];
        __syncthreads();
    }
    if (tid == 0) {
        float m = (float)(red[0] / (double)QE);
        out[QE] = m + 0.25f * m;
    }
}

extern "C" void kernel_launch(void* const* d_in, const int* in_sizes, int n_in,
                              void* d_out, int out_size, void* d_ws, size_t ws_size,
                              hipStream_t stream)
{
    const float* inp = (const float*)d_in[0];
    const float* cb  = (const float*)d_in[1];
    float* out = (float*)d_out;
    char* ws = (char*)d_ws;

    if (ws_size >= WS_REQ) {
        float*    se   = (float*)(ws + SE_OFF);
        _Float16* cbh  = (_Float16*)(ws + CBH_OFF);
        int*      cnt  = (int*)(ws + CNT_OFF);
        int*      hard = (int*)(ws + HARD_OFF);
        float*    rl   = (float*)(ws + RL_OFF);
        double*   part = (double*)(ws + PART_OFF);

        vq_prep<<<4, 256, 0, stream>>>(cb, se, cbh, cnt);
        vq_pass1<<<NBLK, 256, 0, stream>>>(inp, cb, cbh, se, out, hard, cnt, rl);
        vq_pass2<<<512, 256, 0, stream>>>(inp, cb, se, out, hard, cnt, rl);
        vq_lred<<<512, 256, 0, stream>>>(rl, part);
        vq_fin2<<<1, 256, 0, stream>>>(part, out);
    } else {
        float*  se   = (float*)ws;
        double* part = (double*)(ws + 4096);
        vq_norms_fb<<<4, 256, 0, stream>>>(cb, se);
        vq_main_fb<<<NBLK, 256, 0, stream>>>(inp, cb, se, out, part);
        vq_fin_fb<<<1, 256, 0, stream>>>(part, out);
    }
}